// Round 2
// baseline (510.708 us; speedup 1.0000x reference)
//
#include <hip/hip_runtime.h>
#include <hip/hip_bf16.h>
#include <cstdint>
#include <cstddef>

// Problem constants: B=2, L=2048, D_MODEL=1024, D_INNER=2048, D_STATE=16,
// D_CONV=4, DT_RANK=64.  M = B*L = 4096 tokens.
// ALL inputs and the output are FLOAT32 (per reference). MFMA runs on
// bf16-downcast operands with fp32 accumulate (threshold is 2% relative).

typedef __bf16 bf16x8 __attribute__((ext_vector_type(8)));
typedef float f32x4 __attribute__((ext_vector_type(4)));

// load 8 consecutive floats, downcast to bf16x8
__device__ inline bf16x8 cvt8(const float* __restrict__ p) {
    f32x4 a = *(const f32x4*)p;
    f32x4 b = *(const f32x4*)(p + 4);
    bf16x8 o;
    o[0] = (__bf16)a[0]; o[1] = (__bf16)a[1]; o[2] = (__bf16)a[2]; o[3] = (__bf16)a[3];
    o[4] = (__bf16)b[0]; o[5] = (__bf16)b[1]; o[6] = (__bf16)b[2]; o[7] = (__bf16)b[3];
    return o;
}

// ---------------------------------------------------------------------------
// GEMM1: C_bf16[M][ldc(+n0)] = A_f32[M][K] @ B_f32[N][K]^T
// 128x128 tile, BK=32, 256 thr (4 waves x 64x64).
// ---------------------------------------------------------------------------
__global__ __launch_bounds__(256, 2) void gemm_ff_bf(const float* __restrict__ A,
                                                     const float* __restrict__ Bw,
                                                     __bf16* __restrict__ C,
                                                     int K, int ldc) {
    __shared__ __bf16 As[128][32];
    __shared__ __bf16 Bs[128][32];
    const int tid = threadIdx.x;
    const int lane = tid & 63;
    const int wave = tid >> 6;
    const int m0 = blockIdx.x * 128;
    const int n0 = blockIdx.y * 128;
    const int wm = (wave >> 1) * 64;
    const int wn = (wave & 1) * 64;
    const int mrow = lane & 15;
    const int kq = (lane >> 4) * 8;
    const int arow = tid >> 2;
    const int akc = (tid & 3) * 8;

    f32x4 acc[4][4] = {};

    for (int k0 = 0; k0 < K; k0 += 32) {
        *(bf16x8*)&As[arow][akc]      = cvt8(A + (size_t)(m0 + arow) * K + k0 + akc);
        *(bf16x8*)&As[64 + arow][akc] = cvt8(A + (size_t)(m0 + 64 + arow) * K + k0 + akc);
        *(bf16x8*)&Bs[arow][akc]      = cvt8(Bw + (size_t)(n0 + arow) * K + k0 + akc);
        *(bf16x8*)&Bs[64 + arow][akc] = cvt8(Bw + (size_t)(n0 + 64 + arow) * K + k0 + akc);
        __syncthreads();

        bf16x8 af[4], bfr[4];
#pragma unroll
        for (int i = 0; i < 4; ++i) af[i]  = *(const bf16x8*)&As[wm + i * 16 + mrow][kq];
#pragma unroll
        for (int j = 0; j < 4; ++j) bfr[j] = *(const bf16x8*)&Bs[wn + j * 16 + mrow][kq];
#pragma unroll
        for (int i = 0; i < 4; ++i)
#pragma unroll
            for (int j = 0; j < 4; ++j)
                acc[i][j] = __builtin_amdgcn_mfma_f32_16x16x32_bf16(af[i], bfr[j], acc[i][j], 0, 0, 0);
        __syncthreads();
    }
    const int col = lane & 15;
    const int rb = (lane >> 4) * 4;
#pragma unroll
    for (int i = 0; i < 4; ++i)
#pragma unroll
        for (int j = 0; j < 4; ++j)
#pragma unroll
            for (int r = 0; r < 4; ++r)
                C[(size_t)(m0 + wm + i * 16 + rb + r) * ldc + n0 + wn + j * 16 + col] =
                    (__bf16)acc[i][j][r];
}

// ---------------------------------------------------------------------------
// GEMM6: out_f32[M][N] = A_bf16[M][2048] @ B_f32[N][2048]^T
// ---------------------------------------------------------------------------
__global__ __launch_bounds__(256, 2) void gemm_bf_f(const __bf16* __restrict__ A,
                                                    const float* __restrict__ Bw,
                                                    float* __restrict__ C,
                                                    int K, int N) {
    __shared__ __bf16 As[128][32];
    __shared__ __bf16 Bs[128][32];
    const int tid = threadIdx.x;
    const int lane = tid & 63;
    const int wave = tid >> 6;
    const int m0 = blockIdx.x * 128;
    const int n0 = blockIdx.y * 128;
    const int wm = (wave >> 1) * 64;
    const int wn = (wave & 1) * 64;
    const int mrow = lane & 15;
    const int kq = (lane >> 4) * 8;
    const int arow = tid >> 2;
    const int akc = (tid & 3) * 8;

    f32x4 acc[4][4] = {};

    for (int k0 = 0; k0 < K; k0 += 32) {
        *(bf16x8*)&As[arow][akc]      = *(const bf16x8*)(A + (size_t)(m0 + arow) * K + k0 + akc);
        *(bf16x8*)&As[64 + arow][akc] = *(const bf16x8*)(A + (size_t)(m0 + 64 + arow) * K + k0 + akc);
        *(bf16x8*)&Bs[arow][akc]      = cvt8(Bw + (size_t)(n0 + arow) * K + k0 + akc);
        *(bf16x8*)&Bs[64 + arow][akc] = cvt8(Bw + (size_t)(n0 + 64 + arow) * K + k0 + akc);
        __syncthreads();

        bf16x8 af[4], bfr[4];
#pragma unroll
        for (int i = 0; i < 4; ++i) af[i]  = *(const bf16x8*)&As[wm + i * 16 + mrow][kq];
#pragma unroll
        for (int j = 0; j < 4; ++j) bfr[j] = *(const bf16x8*)&Bs[wn + j * 16 + mrow][kq];
#pragma unroll
        for (int i = 0; i < 4; ++i)
#pragma unroll
            for (int j = 0; j < 4; ++j)
                acc[i][j] = __builtin_amdgcn_mfma_f32_16x16x32_bf16(af[i], bfr[j], acc[i][j], 0, 0, 0);
        __syncthreads();
    }
    const int col = lane & 15;
    const int rb = (lane >> 4) * 4;
#pragma unroll
    for (int i = 0; i < 4; ++i)
#pragma unroll
        for (int j = 0; j < 4; ++j)
#pragma unroll
            for (int r = 0; r < 4; ++r)
                C[(size_t)(m0 + wm + i * 16 + rb + r) * N + n0 + wn + j * 16 + col] =
                    acc[i][j][r];
}

// ---------------------------------------------------------------------------
// Causal depthwise conv (K=4) + SiLU.  x_in = xz[:, :2048] (bf16), weights f32.
// ---------------------------------------------------------------------------
__global__ void conv_silu_kernel(const __bf16* __restrict__ xz,
                                 const float* __restrict__ cw,
                                 const float* __restrict__ cb,
                                 __bf16* __restrict__ x) {
    int tid = threadIdx.x;
    int r = blockIdx.x;        // token row 0..4095
    int l = r & 2047;          // position within batch
    int d = tid * 8;

    float acc[8];
#pragma unroll
    for (int i = 0; i < 8; ++i) acc[i] = cb[d + i];

#pragma unroll
    for (int dlt = 0; dlt < 4; ++dlt) {   // x_in[l-dlt] * w[:, 3-dlt]
        if (l - dlt < 0) break;
        bf16x8 v = *(const bf16x8*)(xz + (size_t)(r - dlt) * 4096 + d);
#pragma unroll
        for (int i = 0; i < 8; ++i)
            acc[i] += (float)v[i] * cw[(d + i) * 4 + 3 - dlt];
    }
    bf16x8 o;
#pragma unroll
    for (int i = 0; i < 8; ++i) {
        float s = acc[i];
        s = s / (1.f + __expf(-s));
        o[i] = (__bf16)s;
    }
    *(bf16x8*)(x + (size_t)r * 2048 + d) = o;
}

// ---------------------------------------------------------------------------
// x_p[4096][96] = x_bf16[4096][2048] @ W_x_f32[96][2048]^T -> bf16
// ---------------------------------------------------------------------------
__global__ __launch_bounds__(256, 2) void gemm_xp(const __bf16* __restrict__ A,
                                                  const float* __restrict__ Bw,
                                                  __bf16* __restrict__ C) {
    __shared__ __bf16 As[64][64];
    __shared__ __bf16 Bs[96][64];
    const int tid = threadIdx.x;
    const int lane = tid & 63;
    const int wave = tid >> 6;
    const int m0 = blockIdx.x * 64;
    const int mrow = lane & 15;
    const int kq = (lane >> 4) * 8;

    f32x4 acc[6] = {};

    for (int k0 = 0; k0 < 2048; k0 += 64) {
#pragma unroll
        for (int r = 0; r < 2; ++r) {
            int e = r * 256 + tid;
            int row = e >> 3, kc = e & 7;
            *(bf16x8*)&As[row][kc * 8] =
                *(const bf16x8*)(A + (size_t)(m0 + row) * 2048 + k0 + kc * 8);
        }
#pragma unroll
        for (int r = 0; r < 3; ++r) {
            int e = r * 256 + tid;
            int row = e >> 3, kc = e & 7;
            *(bf16x8*)&Bs[row][kc * 8] = cvt8(Bw + (size_t)row * 2048 + k0 + kc * 8);
        }
        __syncthreads();
#pragma unroll
        for (int kc = 0; kc < 2; ++kc) {
            bf16x8 af = *(const bf16x8*)&As[wave * 16 + mrow][kc * 32 + kq];
#pragma unroll
            for (int j = 0; j < 6; ++j) {
                bf16x8 bfr = *(const bf16x8*)&Bs[j * 16 + mrow][kc * 32 + kq];
                acc[j] = __builtin_amdgcn_mfma_f32_16x16x32_bf16(af, bfr, acc[j], 0, 0, 0);
            }
        }
        __syncthreads();
    }
    const int col = lane & 15;
    const int rb = (lane >> 4) * 4;
#pragma unroll
    for (int j = 0; j < 6; ++j)
#pragma unroll
        for (int r = 0; r < 4; ++r)
            C[(size_t)(m0 + wave * 16 + rb + r) * 96 + j * 16 + col] = (__bf16)acc[j][r];
}

// ---------------------------------------------------------------------------
// dt = softplus(x_p[:, :64] @ W_dt_f32[2048][64]^T + b_dt), written bf16 into
// xz[:, :2048] (row stride 4096) over the consumed x_in half.
// ---------------------------------------------------------------------------
__global__ __launch_bounds__(256, 2) void gemm_dt(const __bf16* __restrict__ xp,
                                                  const float* __restrict__ Wdt,
                                                  const float* __restrict__ bdt,
                                                  __bf16* __restrict__ dt) {
    const int tid = threadIdx.x;
    const int lane = tid & 63;
    const int wave = tid >> 6;
    const int m0 = blockIdx.x * 128 + (wave >> 1) * 64;
    const int n0 = blockIdx.y * 128 + (wave & 1) * 64;
    const int mrow = lane & 15;
    const int kq = (lane >> 4) * 8;

    f32x4 acc[4][4] = {};
#pragma unroll
    for (int kc = 0; kc < 2; ++kc) {
        bf16x8 af[4], bfr[4];
#pragma unroll
        for (int i = 0; i < 4; ++i)
            af[i] = *(const bf16x8*)(xp + (size_t)(m0 + i * 16 + mrow) * 96 + kc * 32 + kq);
#pragma unroll
        for (int j = 0; j < 4; ++j)
            bfr[j] = cvt8(Wdt + (size_t)(n0 + j * 16 + mrow) * 64 + kc * 32 + kq);
#pragma unroll
        for (int i = 0; i < 4; ++i)
#pragma unroll
            for (int j = 0; j < 4; ++j)
                acc[i][j] = __builtin_amdgcn_mfma_f32_16x16x32_bf16(af[i], bfr[j], acc[i][j], 0, 0, 0);
    }
    const int col = lane & 15;
    const int rb = (lane >> 4) * 4;
#pragma unroll
    for (int i = 0; i < 4; ++i)
#pragma unroll
        for (int j = 0; j < 4; ++j) {
            int cc = n0 + j * 16 + col;
            float bias = bdt[cc];
#pragma unroll
            for (int r = 0; r < 4; ++r) {
                float v = acc[i][j][r] + bias;
                float sp = (v > 20.f) ? v : log1pf(__expf(v));
                dt[(size_t)(m0 + i * 16 + rb + r) * 4096 + cc] = (__bf16)sp;
            }
        }
}

// ---------------------------------------------------------------------------
// Selective scan fused with y = (ys + D*x) * silu(z).
// dt lives in xz[:, :2048], z in xz[:, 2048:], x in xq; y written in-place
// over x in xq (each block owns its 16 columns; cells staged to LDS first).
// ---------------------------------------------------------------------------
__global__ __launch_bounds__(256) void scan_kernel(const __bf16* __restrict__ xz,
                                                   __bf16* __restrict__ xq,
                                                   const __bf16* __restrict__ xp,
                                                   const float* __restrict__ A_log,
                                                   const float* __restrict__ Dp) {
    __shared__ __bf16 s_dt[32][16], s_x[32][16], s_B[32][16], s_C[32][16], s_z[32][16];
    __shared__ float s_con[32][16][17];   // [t][d_local][n] (+1 pad)

    const int tid = threadIdx.x;
    const int n = tid & 15;
    const int dl = tid >> 4;
    const int blk = blockIdx.x;
    const int b = blk >> 7;
    const int d0 = (blk & 127) * 16;
    const int d = d0 + dl;
    const int row0 = b * 2048;

    const float Adn = -__expf(A_log[d * 16 + n]);
    float h = 0.f;

    const int tt = tid >> 3;
    const int ee = (tid & 7) * 2;

    for (int t0 = 0; t0 < 2048; t0 += 32) {
        __syncthreads();
        {
            int r = row0 + t0 + tt;
            const __bf16* pdt = xz + (size_t)r * 4096 + d0 + ee;          // dt
            s_dt[tt][ee] = pdt[0]; s_dt[tt][ee + 1] = pdt[1];
            const __bf16* px = xq + (size_t)r * 2048 + d0 + ee;           // x
            s_x[tt][ee] = px[0]; s_x[tt][ee + 1] = px[1];
            const __bf16* pz = xz + (size_t)r * 4096 + 2048 + d0 + ee;    // z
            s_z[tt][ee] = pz[0]; s_z[tt][ee + 1] = pz[1];
            const __bf16* pb = xp + (size_t)r * 96 + 64 + ee;             // B
            s_B[tt][ee] = pb[0]; s_B[tt][ee + 1] = pb[1];
            const __bf16* pc = xp + (size_t)r * 96 + 80 + ee;             // C
            s_C[tt][ee] = pc[0]; s_C[tt][ee + 1] = pc[1];
        }
        __syncthreads();

#pragma unroll
        for (int t = 0; t < 32; ++t) {
            float dtv = (float)s_dt[t][dl];
            float xv  = (float)s_x[t][dl];
            float Bv  = (float)s_B[t][n];
            float Cv  = (float)s_C[t][n];
            float dA = __expf(dtv * Adn);
            h = fmaf(dA, h, dtv * xv * Bv);
            s_con[t][dl][n] = h * Cv;
        }
        __syncthreads();

#pragma unroll
        for (int p = 0; p < 2; ++p) {
            int pt = p * 256 + tid;
            int t = pt >> 4, dd = pt & 15;
            float sum = 0.f;
#pragma unroll
            for (int q = 0; q < 16; ++q) sum += s_con[t][dd][q];
            float xv = (float)s_x[t][dd];
            float zv = (float)s_z[t][dd];
            float Dd = Dp[d0 + dd];
            float yv = (sum + Dd * xv) * (zv / (1.f + __expf(-zv)));
            xq[(size_t)(row0 + t0 + t) * 2048 + d0 + dd] = (__bf16)yv;   // y in-place
        }
    }
}

// ---------------------------------------------------------------------------
extern "C" void kernel_launch(void* const* d_in, const int* in_sizes, int n_in,
                              void* d_out, int out_size, void* d_ws, size_t ws_size,
                              hipStream_t stream) {
    const float* u      = (const float*)d_in[0];   // [2,2048,1024]
    const float* W_in   = (const float*)d_in[1];   // [4096,1024]
    const float* W_out  = (const float*)d_in[2];   // [1024,2048]
    const float* conv_w = (const float*)d_in[3];   // [2048,4]
    const float* conv_b = (const float*)d_in[4];   // [2048]
    const float* W_x    = (const float*)d_in[5];   // [96,2048]
    const float* W_dt   = (const float*)d_in[6];   // [2048,64]
    const float* b_dt   = (const float*)d_in[7];   // [2048]
    const float* A_log  = (const float*)d_in[8];   // [2048,16]
    const float* D_p    = (const float*)d_in[9];   // [2048]
    float* out = (float*)d_out;                    // [2,2048,1024] f32

    // workspace (bf16 intermediates), total 51.1 MB:
    __bf16* xz = (__bf16*)d_ws;                    // [4096][4096]; cols<2048: x_in then dt; cols>=2048: z
    __bf16* xq = xz + (size_t)4096 * 4096;         // [4096][2048]; x then y (in-place)
    __bf16* xp = xq + (size_t)4096 * 2048;         // [4096][96]

    // 1. xz = bf16(u) @ bf16(W_in)^T       (M=4096, N=4096, K=1024)
    gemm_ff_bf<<<dim3(32, 32), 256, 0, stream>>>(u, W_in, xz, 1024, 4096);
    // 2. x = silu(causal_conv(x_in))
    conv_silu_kernel<<<4096, 256, 0, stream>>>(xz, conv_w, conv_b, xq);
    // 3. x_p = x @ bf16(W_x)^T             (M=4096, N=96, K=2048)
    gemm_xp<<<64, 256, 0, stream>>>(xq, W_x, xp);
    // 4. dt = softplus(x_p[:,:64] @ bf16(W_dt)^T + b_dt) -> xz[:, :2048]
    gemm_dt<<<dim3(32, 16), 256, 0, stream>>>(xp, W_dt, b_dt, xz);
    // 5. selective scan + gating, y -> xq
    scan_kernel<<<256, 256, 0, stream>>>(xz, xq, xp, A_log, D_p);
    // 6. out = y @ bf16(W_out)^T -> f32    (M=4096, N=1024, K=2048)
    gemm_bf_f<<<dim3(32, 8), 256, 0, stream>>>(xq, W_out, out, 2048, 1024);
}

// Round 3
// 469.611 us; speedup vs baseline: 1.0875x; 1.0875x over previous
//
#include <hip/hip_runtime.h>
#include <hip/hip_bf16.h>
#include <cstdint>
#include <cstddef>

// B=2, L=2048, D_MODEL=1024, D_INNER=2048, D_STATE=16, D_CONV=4, DT_RANK=64
// M = B*L = 4096. All inputs/output fp32; internals bf16 (threshold 2% rel).
// R3: (1) 3-phase chunked selective scan (16 chunks x 128 steps) — fixes the
//     1-block/CU serialization seen in R2 (156.8us, 11.5% occ, VALU 32%).
// (2) pre-convert u/W_in/W_out to bf16 + m97-style global_load_lds GEMMs.

typedef __bf16 bf16x8 __attribute__((ext_vector_type(8)));
typedef __bf16 bf16x4 __attribute__((ext_vector_type(4)));
typedef float f32x4 __attribute__((ext_vector_type(4)));

__device__ __forceinline__ bf16x8 cvt8(const float* __restrict__ p) {
    f32x4 a = *(const f32x4*)p;
    f32x4 b = *(const f32x4*)(p + 4);
    bf16x8 o;
    o[0] = (__bf16)a[0]; o[1] = (__bf16)a[1]; o[2] = (__bf16)a[2]; o[3] = (__bf16)a[3];
    o[4] = (__bf16)b[0]; o[5] = (__bf16)b[1]; o[6] = (__bf16)b[2]; o[7] = (__bf16)b[3];
    return o;
}

// async global->LDS, 16B per lane; lds base must be wave-uniform (m97 pattern)
__device__ __forceinline__ void gll16(const __bf16* g, __bf16* l) {
    __builtin_amdgcn_global_load_lds(
        (const __attribute__((address_space(1))) void*)g,
        (__attribute__((address_space(3))) void*)l, 16, 0, 0);
}

// ---------------------------------------------------------------------------
// f32 -> bf16 bulk convert (8 elems/thread)
// ---------------------------------------------------------------------------
__global__ void cvt_kernel(const float* __restrict__ src, __bf16* __restrict__ dst, int n8) {
    int i = blockIdx.x * 256 + threadIdx.x;
    if (i < n8) *(bf16x8*)(dst + (size_t)i * 8) = cvt8(src + (size_t)i * 8);
}

// ---------------------------------------------------------------------------
// m97-style GEMM: C[M][ldc] = A[M][K] @ B[N][K]^T, bf16 in, 128x128 tile,
// BK=32, 256 thr, global_load_lds width-16 staging. Two epilogue variants.
// ---------------------------------------------------------------------------
#define GEMM_BODY(EPILOG)                                                       \
    __shared__ __bf16 As[128][32];                                              \
    __shared__ __bf16 Bs[128][32];                                              \
    const int tid = threadIdx.x, lane = tid & 63, wave = tid >> 6;              \
    const int m0 = blockIdx.x * 128, n0 = blockIdx.y * 128;                     \
    const int wm = (wave >> 1) * 64, wn = (wave & 1) * 64;                      \
    const int mrow = lane & 15, kq = (lane >> 4) * 8;                           \
    const int sr = wave * 32 + (lane >> 2);                                     \
    const int sk = (lane & 3) * 8;                                              \
    const __bf16* Ag0 = A + (size_t)(m0 + sr) * K + sk;                         \
    const __bf16* Ag1 = Ag0 + (size_t)16 * K;                                   \
    const __bf16* Bg0 = Bw + (size_t)(n0 + sr) * K + sk;                        \
    const __bf16* Bg1 = Bg0 + (size_t)16 * K;                                   \
    __bf16* La0 = &As[wave * 32][0];                                            \
    __bf16* La1 = &As[wave * 32 + 16][0];                                       \
    __bf16* Lb0 = &Bs[wave * 32][0];                                            \
    __bf16* Lb1 = &Bs[wave * 32 + 16][0];                                       \
    f32x4 acc[4][4] = {};                                                       \
    for (int k0 = 0; k0 < K; k0 += 32) {                                        \
        gll16(Ag0 + k0, La0);                                                   \
        gll16(Ag1 + k0, La1);                                                   \
        gll16(Bg0 + k0, Lb0);                                                   \
        gll16(Bg1 + k0, Lb1);                                                   \
        __syncthreads();                                                        \
        bf16x8 af[4], bfr[4];                                                   \
        _Pragma("unroll")                                                       \
        for (int i = 0; i < 4; ++i) af[i]  = *(const bf16x8*)&As[wm + i * 16 + mrow][kq]; \
        _Pragma("unroll")                                                       \
        for (int j = 0; j < 4; ++j) bfr[j] = *(const bf16x8*)&Bs[wn + j * 16 + mrow][kq]; \
        _Pragma("unroll")                                                       \
        for (int i = 0; i < 4; ++i)                                             \
            _Pragma("unroll")                                                   \
            for (int j = 0; j < 4; ++j)                                         \
                acc[i][j] = __builtin_amdgcn_mfma_f32_16x16x32_bf16(af[i], bfr[j], acc[i][j], 0, 0, 0); \
        __syncthreads();                                                        \
    }                                                                           \
    const int col = lane & 15;                                                  \
    const int rb = (lane >> 4) * 4;                                             \
    _Pragma("unroll")                                                           \
    for (int i = 0; i < 4; ++i)                                                 \
        _Pragma("unroll")                                                       \
        for (int j = 0; j < 4; ++j)                                             \
            _Pragma("unroll")                                                   \
            for (int r = 0; r < 4; ++r)                                         \
                EPILOG;

__global__ __launch_bounds__(256, 2) void gemm_async_bf(const __bf16* __restrict__ A,
                                                        const __bf16* __restrict__ Bw,
                                                        __bf16* __restrict__ C,
                                                        int K, int ldc) {
    GEMM_BODY(C[(size_t)(m0 + wm + i * 16 + rb + r) * ldc + n0 + wn + j * 16 + col] = (__bf16)acc[i][j][r])
}

__global__ __launch_bounds__(256, 2) void gemm_async_f32(const __bf16* __restrict__ A,
                                                         const __bf16* __restrict__ Bw,
                                                         float* __restrict__ C,
                                                         int K, int ldc) {
    GEMM_BODY(C[(size_t)(m0 + wm + i * 16 + rb + r) * ldc + n0 + wn + j * 16 + col] = acc[i][j][r])
}

// ---------------------------------------------------------------------------
// Causal depthwise conv (K=4) + SiLU.  x_in = xz[:, :2048] (bf16), weights f32.
// ---------------------------------------------------------------------------
__global__ void conv_silu_kernel(const __bf16* __restrict__ xz,
                                 const float* __restrict__ cw,
                                 const float* __restrict__ cb,
                                 __bf16* __restrict__ x) {
    int tid = threadIdx.x;
    int r = blockIdx.x;
    int l = r & 2047;
    int d = tid * 8;

    float acc[8];
#pragma unroll
    for (int i = 0; i < 8; ++i) acc[i] = cb[d + i];

#pragma unroll
    for (int dlt = 0; dlt < 4; ++dlt) {
        if (l - dlt < 0) break;
        bf16x8 v = *(const bf16x8*)(xz + (size_t)(r - dlt) * 4096 + d);
#pragma unroll
        for (int i = 0; i < 8; ++i)
            acc[i] += (float)v[i] * cw[(d + i) * 4 + 3 - dlt];
    }
    bf16x8 o;
#pragma unroll
    for (int i = 0; i < 8; ++i) {
        float s = acc[i];
        s = s / (1.f + __expf(-s));
        o[i] = (__bf16)s;
    }
    *(bf16x8*)(x + (size_t)r * 2048 + d) = o;
}

// ---------------------------------------------------------------------------
// x_p[4096][96] = x_bf16 @ W_x_f32^T -> bf16
// ---------------------------------------------------------------------------
__global__ __launch_bounds__(256, 2) void gemm_xp(const __bf16* __restrict__ A,
                                                  const float* __restrict__ Bw,
                                                  __bf16* __restrict__ C) {
    __shared__ __bf16 As[64][64];
    __shared__ __bf16 Bs[96][64];
    const int tid = threadIdx.x;
    const int lane = tid & 63;
    const int wave = tid >> 6;
    const int m0 = blockIdx.x * 64;
    const int mrow = lane & 15;
    const int kq = (lane >> 4) * 8;

    f32x4 acc[6] = {};

    for (int k0 = 0; k0 < 2048; k0 += 64) {
#pragma unroll
        for (int r = 0; r < 2; ++r) {
            int e = r * 256 + tid;
            int row = e >> 3, kc = e & 7;
            *(bf16x8*)&As[row][kc * 8] =
                *(const bf16x8*)(A + (size_t)(m0 + row) * 2048 + k0 + kc * 8);
        }
#pragma unroll
        for (int r = 0; r < 3; ++r) {
            int e = r * 256 + tid;
            int row = e >> 3, kc = e & 7;
            *(bf16x8*)&Bs[row][kc * 8] = cvt8(Bw + (size_t)row * 2048 + k0 + kc * 8);
        }
        __syncthreads();
#pragma unroll
        for (int kc = 0; kc < 2; ++kc) {
            bf16x8 af = *(const bf16x8*)&As[wave * 16 + mrow][kc * 32 + kq];
#pragma unroll
            for (int j = 0; j < 6; ++j) {
                bf16x8 bfr = *(const bf16x8*)&Bs[j * 16 + mrow][kc * 32 + kq];
                acc[j] = __builtin_amdgcn_mfma_f32_16x16x32_bf16(af, bfr, acc[j], 0, 0, 0);
            }
        }
        __syncthreads();
    }
    const int col = lane & 15;
    const int rb = (lane >> 4) * 4;
#pragma unroll
    for (int j = 0; j < 6; ++j)
#pragma unroll
        for (int r = 0; r < 4; ++r)
            C[(size_t)(m0 + wave * 16 + rb + r) * 96 + j * 16 + col] = (__bf16)acc[j][r];
}

// ---------------------------------------------------------------------------
// dt = softplus(x_p[:, :64] @ W_dt^T + b_dt) -> bf16 into xz[:, :2048]
// ---------------------------------------------------------------------------
__global__ __launch_bounds__(256, 2) void gemm_dt(const __bf16* __restrict__ xp,
                                                  const float* __restrict__ Wdt,
                                                  const float* __restrict__ bdt,
                                                  __bf16* __restrict__ dt) {
    const int tid = threadIdx.x;
    const int lane = tid & 63;
    const int wave = tid >> 6;
    const int m0 = blockIdx.x * 128 + (wave >> 1) * 64;
    const int n0 = blockIdx.y * 128 + (wave & 1) * 64;
    const int mrow = lane & 15;
    const int kq = (lane >> 4) * 8;

    f32x4 acc[4][4] = {};
#pragma unroll
    for (int kc = 0; kc < 2; ++kc) {
        bf16x8 af[4], bfr[4];
#pragma unroll
        for (int i = 0; i < 4; ++i)
            af[i] = *(const bf16x8*)(xp + (size_t)(m0 + i * 16 + mrow) * 96 + kc * 32 + kq);
#pragma unroll
        for (int j = 0; j < 4; ++j)
            bfr[j] = cvt8(Wdt + (size_t)(n0 + j * 16 + mrow) * 64 + kc * 32 + kq);
#pragma unroll
        for (int i = 0; i < 4; ++i)
#pragma unroll
            for (int j = 0; j < 4; ++j)
                acc[i][j] = __builtin_amdgcn_mfma_f32_16x16x32_bf16(af[i], bfr[j], acc[i][j], 0, 0, 0);
    }
    const int col = lane & 15;
    const int rb = (lane >> 4) * 4;
#pragma unroll
    for (int i = 0; i < 4; ++i)
#pragma unroll
        for (int j = 0; j < 4; ++j) {
            int cc = n0 + j * 16 + col;
            float bias = bdt[cc];
#pragma unroll
            for (int r = 0; r < 4; ++r) {
                float v = acc[i][j][r] + bias;
                float sp = (v > 20.f) ? v : log1pf(__expf(v));
                dt[(size_t)(m0 + i * 16 + rb + r) * 4096 + cc] = (__bf16)sp;
            }
        }
}

// ---------------------------------------------------------------------------
// Chunked scan. 16 chunks x 128 steps. Block = 16 d x 16 n (256 thr).
// Grid = 2 b x 16 c x 128 d-tiles = 4096 blocks.
// Phase 1: local scan from h=0 -> h_end, plus dtsum (chunk transition =
// exp(Adn * sum(dt)) because dA is diagonal).
// ---------------------------------------------------------------------------
__global__ __launch_bounds__(256) void scan_p1(const __bf16* __restrict__ xz,
                                               const __bf16* __restrict__ xq,
                                               const __bf16* __restrict__ xp,
                                               const float* __restrict__ A_log,
                                               float* __restrict__ h_end,
                                               float* __restrict__ dtsum) {
    __shared__ __bf16 s_dt[128][16], s_x[128][16], s_B[128][16];
    const int tid = threadIdx.x;
    const int blk = blockIdx.x;
    const int b = blk >> 11, c = (blk >> 7) & 15, d0 = (blk & 127) * 16;
    const int n = tid & 15, dl = tid >> 4;
    const int row0 = b * 2048 + c * 128;

    const int rr = tid >> 2, cc = (tid & 3) * 4;
#pragma unroll
    for (int i = 0; i < 2; ++i) {
        int t = rr + i * 64;
        size_t r = (size_t)(row0 + t);
        *(bf16x4*)&s_dt[t][cc] = *(const bf16x4*)(xz + r * 4096 + d0 + cc);
        *(bf16x4*)&s_x[t][cc]  = *(const bf16x4*)(xq + r * 2048 + d0 + cc);
        *(bf16x4*)&s_B[t][cc]  = *(const bf16x4*)(xp + r * 96 + 64 + cc);
    }
    const float Adn = -__expf(A_log[(d0 + dl) * 16 + n]);
    __syncthreads();

    float h = 0.f, ds = 0.f;
#pragma unroll 16
    for (int t = 0; t < 128; ++t) {
        float dtv = (float)s_dt[t][dl];
        float dA = __expf(dtv * Adn);
        h = fmaf(dA, h, dtv * (float)s_x[t][dl] * (float)s_B[t][n]);
        ds += dtv;
    }
    size_t base = (size_t)(b * 16 + c) * 2048 + d0;
    h_end[(base + dl) * 16 + n] = h;
    if (n == 0) dtsum[base + dl] = ds;
}

// Phase 2: prefix over 16 chunks per (b,d,n). 65536 threads.
__global__ __launch_bounds__(256) void scan_p2(const float* __restrict__ A_log,
                                               const float* __restrict__ dtsum,
                                               const float* __restrict__ h_end,
                                               float* __restrict__ h_in) {
    int idx = blockIdx.x * 256 + threadIdx.x;     // 0..65535
    int b = idx >> 15, rem = idx & 32767;
    int d = rem >> 4;
    float Adn = -__expf(A_log[rem]);
    float h = 0.f;
#pragma unroll
    for (int c = 0; c < 16; ++c) {
        size_t base = ((size_t)(b * 16 + c) << 15) + rem;
        h_in[base] = h;
        float P = __expf(Adn * dtsum[((size_t)(b * 16 + c) << 11) + d]);
        h = fmaf(P, h, h_end[base]);
    }
}

// Phase 3: rerun scan from h_in, produce y = (C.h + D*x)*silu(z), in-place
// over x in xq (block-exclusive cells, x staged to LDS first).
__global__ __launch_bounds__(256) void scan_p3(const __bf16* __restrict__ xz,
                                               __bf16* __restrict__ xq,
                                               const __bf16* __restrict__ xp,
                                               const float* __restrict__ A_log,
                                               const float* __restrict__ Dp,
                                               const float* __restrict__ h_in) {
    __shared__ __bf16 s_dt[128][16], s_x[128][16], s_B[128][16], s_C[128][16], s_z[128][16];
    __shared__ float s_con[16][16][17];
    const int tid = threadIdx.x;
    const int blk = blockIdx.x;
    const int b = blk >> 11, c = (blk >> 7) & 15, d0 = (blk & 127) * 16;
    const int n = tid & 15, dl = tid >> 4;
    const int row0 = b * 2048 + c * 128;

    const int rr = tid >> 2, cc = (tid & 3) * 4;
#pragma unroll
    for (int i = 0; i < 2; ++i) {
        int t = rr + i * 64;
        size_t r = (size_t)(row0 + t);
        *(bf16x4*)&s_dt[t][cc] = *(const bf16x4*)(xz + r * 4096 + d0 + cc);
        *(bf16x4*)&s_x[t][cc]  = *(const bf16x4*)(xq + r * 2048 + d0 + cc);
        *(bf16x4*)&s_z[t][cc]  = *(const bf16x4*)(xz + r * 4096 + 2048 + d0 + cc);
        *(bf16x4*)&s_B[t][cc]  = *(const bf16x4*)(xp + r * 96 + 64 + cc);
        *(bf16x4*)&s_C[t][cc]  = *(const bf16x4*)(xp + r * 96 + 80 + cc);
    }
    const float Adn = -__expf(A_log[(d0 + dl) * 16 + n]);
    float h = h_in[((size_t)(b * 16 + c) * 2048 + d0 + dl) * 16 + n];
    const float Dd = Dp[d0 + n];          // epilogue dd == n mapping
    __syncthreads();

    for (int s = 0; s < 8; ++s) {
#pragma unroll
        for (int t = 0; t < 16; ++t) {
            int ts = s * 16 + t;
            float dtv = (float)s_dt[ts][dl];
            float dA = __expf(dtv * Adn);
            h = fmaf(dA, h, dtv * (float)s_x[ts][dl] * (float)s_B[ts][n]);
            s_con[t][dl][n] = h * (float)s_C[ts][n];
        }
        __syncthreads();
        {
            int t = tid >> 4, dd = tid & 15;
            int ts = s * 16 + t;
            float sum = 0.f;
#pragma unroll
            for (int q = 0; q < 16; ++q) sum += s_con[t][dd][q];
            float xv = (float)s_x[ts][dd];
            float zv = (float)s_z[ts][dd];
            float yv = (sum + Dd * xv) * (zv / (1.f + __expf(-zv)));
            xq[((size_t)row0 + ts) * 2048 + d0 + dd] = (__bf16)yv;
        }
        __syncthreads();
    }
}

// ---------------------------------------------------------------------------
extern "C" void kernel_launch(void* const* d_in, const int* in_sizes, int n_in,
                              void* d_out, int out_size, void* d_ws, size_t ws_size,
                              hipStream_t stream) {
    const float* u      = (const float*)d_in[0];
    const float* W_in   = (const float*)d_in[1];
    const float* W_out  = (const float*)d_in[2];
    const float* conv_w = (const float*)d_in[3];
    const float* conv_b = (const float*)d_in[4];
    const float* W_x    = (const float*)d_in[5];
    const float* W_dt   = (const float*)d_in[6];
    const float* b_dt   = (const float*)d_in[7];
    const float* A_log  = (const float*)d_in[8];
    const float* D_p    = (const float*)d_in[9];
    float* out = (float*)d_out;                    // [4096][1024] f32

    // ws (bf16), 63.7 MB total:
    __bf16* xz  = (__bf16*)d_ws;                   // [4096][4096]: x_in->dt | z
    __bf16* xq  = xz + (size_t)4096 * 4096;        // [4096][2048]: x -> y
    __bf16* xp  = xq + (size_t)4096 * 2048;        // [4096][96]
    __bf16* Wib = xp + (size_t)4096 * 96;          // W_in bf16 [4096][1024]
    __bf16* Wob = Wib + (size_t)4096 * 1024;       // W_out bf16 [1024][2048]

    // d_out doubles as scratch (dead until final GEMM):
    __bf16* ub    = (__bf16*)d_out;                // u bf16, 8 MB, dead after gemm1
    float* dtsum  = (float*)d_out;                 // 256 KB, written after gemm1
    float* h_end  = (float*)d_out + 2097152;       // 4 MB
    float* h_in   = (float*)d_out + 3145728;       // 4 MB

    cvt_kernel<<<2048, 256, 0, stream>>>(u, ub, 524288);
    cvt_kernel<<<2048, 256, 0, stream>>>(W_in, Wib, 524288);
    cvt_kernel<<<1024, 256, 0, stream>>>(W_out, Wob, 262144);

    // 1. xz = ub @ Wib^T  (M=4096,N=4096,K=1024)
    gemm_async_bf<<<dim3(32, 32), 256, 0, stream>>>(ub, Wib, xz, 1024, 4096);
    // 2. x = silu(conv(x_in))
    conv_silu_kernel<<<4096, 256, 0, stream>>>(xz, conv_w, conv_b, xq);
    // 3. x_p
    gemm_xp<<<64, 256, 0, stream>>>(xq, W_x, xp);
    // 4. dt -> xz[:, :2048]
    gemm_dt<<<dim3(32, 16), 256, 0, stream>>>(xp, W_dt, b_dt, xz);
    // 5. chunked scan
    scan_p1<<<4096, 256, 0, stream>>>(xz, xq, xp, A_log, h_end, dtsum);
    scan_p2<<<256, 256, 0, stream>>>(A_log, dtsum, h_end, h_in);
    scan_p3<<<4096, 256, 0, stream>>>(xz, xq, xp, A_log, D_p, h_in);
    // 6. out = y @ Wob^T  (M=4096,N=1024,K=2048)
    gemm_async_f32<<<dim3(32, 8), 256, 0, stream>>>(xq, Wob, out, 2048, 1024);
}

// Round 4
// 392.943 us; speedup vs baseline: 1.2997x; 1.1951x over previous
//
#include <hip/hip_runtime.h>
#include <hip/hip_bf16.h>
#include <cstdint>
#include <cstddef>

// B=2, L=2048, D_MODEL=1024, D_INNER=2048, D_STATE=16, D_CONV=4, DT_RANK=64
// M = B*L = 4096. All inputs/output fp32; internals bf16.
// R4: (1) gemm_xp split-K x8 (was 84.5us at 2.8% occupancy);
//     (2) scan p1/p3: 4 states/thread + DPP quad-perm n-reduction, packed
//         u32 LDS operands, b128 staging (was instr-count bound, 81.6us).

typedef __bf16 bf16x8 __attribute__((ext_vector_type(8)));
typedef __bf16 bf16x4 __attribute__((ext_vector_type(4)));
typedef float f32x4 __attribute__((ext_vector_type(4)));
typedef unsigned int u32x4 __attribute__((ext_vector_type(4)));

__device__ __forceinline__ bf16x8 cvt8(const float* __restrict__ p) {
    f32x4 a = *(const f32x4*)p;
    f32x4 b = *(const f32x4*)(p + 4);
    bf16x8 o;
    o[0] = (__bf16)a[0]; o[1] = (__bf16)a[1]; o[2] = (__bf16)a[2]; o[3] = (__bf16)a[3];
    o[4] = (__bf16)b[0]; o[5] = (__bf16)b[1]; o[6] = (__bf16)b[2]; o[7] = (__bf16)b[3];
    return o;
}

__device__ __forceinline__ void gll16(const __bf16* g, __bf16* l) {
    __builtin_amdgcn_global_load_lds(
        (const __attribute__((address_space(1))) void*)g,
        (__attribute__((address_space(3))) void*)l, 16, 0, 0);
}

__device__ __forceinline__ uint32_t packbf(__bf16 lo, __bf16 hi) {
    uint16_t a = __builtin_bit_cast(uint16_t, lo);
    uint16_t b = __builtin_bit_cast(uint16_t, hi);
    return (uint32_t)a | ((uint32_t)b << 16);
}
__device__ __forceinline__ float lo2f(uint32_t u) { return __builtin_bit_cast(float, u << 16); }
__device__ __forceinline__ float hi2f(uint32_t u) { return __builtin_bit_cast(float, u & 0xffff0000u); }

// quad_perm DPP add: v += perm(v). 0xB1 = xor1 [1,0,3,2]; 0x4E = xor2 [2,3,0,1]
template<int CTRL>
__device__ __forceinline__ float qp_add(float v) {
    int r = __builtin_amdgcn_update_dpp(0, __builtin_bit_cast(int, v), CTRL, 0xF, 0xF, true);
    return v + __builtin_bit_cast(float, r);
}

// ---------------------------------------------------------------------------
__global__ void cvt_kernel(const float* __restrict__ src, __bf16* __restrict__ dst, int n8) {
    int i = blockIdx.x * 256 + threadIdx.x;
    if (i < n8) *(bf16x8*)(dst + (size_t)i * 8) = cvt8(src + (size_t)i * 8);
}

// ---------------------------------------------------------------------------
// m97-style GEMM: C[M][ldc] = A[M][K] @ B[N][K]^T, bf16 in, 128x128 tile.
// ---------------------------------------------------------------------------
#define GEMM_BODY(EPILOG)                                                       \
    __shared__ __bf16 As[128][32];                                              \
    __shared__ __bf16 Bs[128][32];                                              \
    const int tid = threadIdx.x, lane = tid & 63, wave = tid >> 6;              \
    const int m0 = blockIdx.x * 128, n0 = blockIdx.y * 128;                     \
    const int wm = (wave >> 1) * 64, wn = (wave & 1) * 64;                      \
    const int mrow = lane & 15, kq = (lane >> 4) * 8;                           \
    const int sr = wave * 32 + (lane >> 2);                                     \
    const int sk = (lane & 3) * 8;                                              \
    const __bf16* Ag0 = A + (size_t)(m0 + sr) * K + sk;                         \
    const __bf16* Ag1 = Ag0 + (size_t)16 * K;                                   \
    const __bf16* Bg0 = Bw + (size_t)(n0 + sr) * K + sk;                        \
    const __bf16* Bg1 = Bg0 + (size_t)16 * K;                                   \
    __bf16* La0 = &As[wave * 32][0];                                            \
    __bf16* La1 = &As[wave * 32 + 16][0];                                       \
    __bf16* Lb0 = &Bs[wave * 32][0];                                            \
    __bf16* Lb1 = &Bs[wave * 32 + 16][0];                                       \
    f32x4 acc[4][4] = {};                                                       \
    for (int k0 = 0; k0 < K; k0 += 32) {                                        \
        gll16(Ag0 + k0, La0);                                                   \
        gll16(Ag1 + k0, La1);                                                   \
        gll16(Bg0 + k0, Lb0);                                                   \
        gll16(Bg1 + k0, Lb1);                                                   \
        __syncthreads();                                                        \
        bf16x8 af[4], bfr[4];                                                   \
        _Pragma("unroll")                                                       \
        for (int i = 0; i < 4; ++i) af[i]  = *(const bf16x8*)&As[wm + i * 16 + mrow][kq]; \
        _Pragma("unroll")                                                       \
        for (int j = 0; j < 4; ++j) bfr[j] = *(const bf16x8*)&Bs[wn + j * 16 + mrow][kq]; \
        _Pragma("unroll")                                                       \
        for (int i = 0; i < 4; ++i)                                             \
            _Pragma("unroll")                                                   \
            for (int j = 0; j < 4; ++j)                                         \
                acc[i][j] = __builtin_amdgcn_mfma_f32_16x16x32_bf16(af[i], bfr[j], acc[i][j], 0, 0, 0); \
        __syncthreads();                                                        \
    }                                                                           \
    const int col = lane & 15;                                                  \
    const int rb = (lane >> 4) * 4;                                             \
    _Pragma("unroll")                                                           \
    for (int i = 0; i < 4; ++i)                                                 \
        _Pragma("unroll")                                                       \
        for (int j = 0; j < 4; ++j)                                             \
            _Pragma("unroll")                                                   \
            for (int r = 0; r < 4; ++r)                                         \
                EPILOG;

__global__ __launch_bounds__(256, 2) void gemm_async_bf(const __bf16* __restrict__ A,
                                                        const __bf16* __restrict__ Bw,
                                                        __bf16* __restrict__ C,
                                                        int K, int ldc) {
    GEMM_BODY(C[(size_t)(m0 + wm + i * 16 + rb + r) * ldc + n0 + wn + j * 16 + col] = (__bf16)acc[i][j][r])
}

__global__ __launch_bounds__(256, 2) void gemm_async_f32(const __bf16* __restrict__ A,
                                                         const __bf16* __restrict__ Bw,
                                                         float* __restrict__ C,
                                                         int K, int ldc) {
    GEMM_BODY(C[(size_t)(m0 + wm + i * 16 + rb + r) * ldc + n0 + wn + j * 16 + col] = acc[i][j][r])
}

// ---------------------------------------------------------------------------
// Causal depthwise conv (K=4) + SiLU
// ---------------------------------------------------------------------------
__global__ void conv_silu_kernel(const __bf16* __restrict__ xz,
                                 const float* __restrict__ cw,
                                 const float* __restrict__ cb,
                                 __bf16* __restrict__ x) {
    int tid = threadIdx.x;
    int r = blockIdx.x;
    int l = r & 2047;
    int d = tid * 8;

    float acc[8];
#pragma unroll
    for (int i = 0; i < 8; ++i) acc[i] = cb[d + i];

#pragma unroll
    for (int dlt = 0; dlt < 4; ++dlt) {
        if (l - dlt < 0) break;
        bf16x8 v = *(const bf16x8*)(xz + (size_t)(r - dlt) * 4096 + d);
#pragma unroll
        for (int i = 0; i < 8; ++i)
            acc[i] += (float)v[i] * cw[(d + i) * 4 + 3 - dlt];
    }
    bf16x8 o;
#pragma unroll
    for (int i = 0; i < 8; ++i) {
        float s = acc[i];
        s = s / (1.f + __expf(-s));
        o[i] = (__bf16)s;
    }
    *(bf16x8*)(x + (size_t)r * 2048 + d) = o;
}

// ---------------------------------------------------------------------------
// gemm_xp split-K: P[ks][4096][96] partial = x[:, ks*256:(ks+1)*256] @ Wx^T
// grid (64 m-tiles, 8 k-slices), block 256.
// ---------------------------------------------------------------------------
__global__ __launch_bounds__(256, 2) void gemm_xp_split(const __bf16* __restrict__ A,
                                                        const __bf16* __restrict__ Bw,
                                                        float* __restrict__ P) {
    __shared__ __bf16 As[64][64];
    __shared__ __bf16 Bs[96][64];
    const int tid = threadIdx.x;
    const int lane = tid & 63;
    const int wave = tid >> 6;
    const int m0 = blockIdx.x * 64;
    const int kb = blockIdx.y * 256;
    const int mrow = lane & 15;
    const int kq = (lane >> 4) * 8;

    f32x4 acc[6] = {};

    for (int k0 = kb; k0 < kb + 256; k0 += 64) {
#pragma unroll
        for (int r = 0; r < 2; ++r) {
            int e = r * 256 + tid;
            int row = e >> 3, kc = e & 7;
            *(bf16x8*)&As[row][kc * 8] =
                *(const bf16x8*)(A + (size_t)(m0 + row) * 2048 + k0 + kc * 8);
        }
#pragma unroll
        for (int r = 0; r < 3; ++r) {
            int e = r * 256 + tid;
            int row = e >> 3, kc = e & 7;
            *(bf16x8*)&Bs[row][kc * 8] =
                *(const bf16x8*)(Bw + (size_t)row * 2048 + k0 + kc * 8);
        }
        __syncthreads();
#pragma unroll
        for (int kc = 0; kc < 2; ++kc) {
            bf16x8 af = *(const bf16x8*)&As[wave * 16 + mrow][kc * 32 + kq];
#pragma unroll
            for (int j = 0; j < 6; ++j) {
                bf16x8 bfr = *(const bf16x8*)&Bs[j * 16 + mrow][kc * 32 + kq];
                acc[j] = __builtin_amdgcn_mfma_f32_16x16x32_bf16(af, bfr, acc[j], 0, 0, 0);
            }
        }
        __syncthreads();
    }
    const int col = lane & 15;
    const int rb = (lane >> 4) * 4;
    float* Pb = P + (size_t)blockIdx.y * 4096 * 96;
#pragma unroll
    for (int j = 0; j < 6; ++j)
#pragma unroll
        for (int r = 0; r < 4; ++r)
            Pb[(size_t)(m0 + wave * 16 + rb + r) * 96 + j * 16 + col] = acc[j][r];
}

// reduce 8 partials -> xp bf16. grid 4096 (one row), block 128 (96 active).
__global__ void xp_reduce(const float* __restrict__ P, __bf16* __restrict__ xp) {
    int m = blockIdx.x, c = threadIdx.x;
    if (c < 96) {
        float s = 0.f;
#pragma unroll
        for (int k = 0; k < 8; ++k) s += P[(size_t)k * 4096 * 96 + (size_t)m * 96 + c];
        xp[(size_t)m * 96 + c] = (__bf16)s;
    }
}

// ---------------------------------------------------------------------------
// dt = softplus(x_p[:, :64] @ W_dt^T + b_dt) -> bf16 into xz[:, :2048]
// ---------------------------------------------------------------------------
__global__ __launch_bounds__(256, 2) void gemm_dt(const __bf16* __restrict__ xp,
                                                  const __bf16* __restrict__ Wdt,
                                                  const float* __restrict__ bdt,
                                                  __bf16* __restrict__ dt) {
    const int tid = threadIdx.x;
    const int lane = tid & 63;
    const int wave = tid >> 6;
    const int m0 = blockIdx.x * 128 + (wave >> 1) * 64;
    const int n0 = blockIdx.y * 128 + (wave & 1) * 64;
    const int mrow = lane & 15;
    const int kq = (lane >> 4) * 8;

    f32x4 acc[4][4] = {};
#pragma unroll
    for (int kc = 0; kc < 2; ++kc) {
        bf16x8 af[4], bfr[4];
#pragma unroll
        for (int i = 0; i < 4; ++i)
            af[i] = *(const bf16x8*)(xp + (size_t)(m0 + i * 16 + mrow) * 96 + kc * 32 + kq);
#pragma unroll
        for (int j = 0; j < 4; ++j)
            bfr[j] = *(const bf16x8*)(Wdt + (size_t)(n0 + j * 16 + mrow) * 64 + kc * 32 + kq);
#pragma unroll
        for (int i = 0; i < 4; ++i)
#pragma unroll
            for (int j = 0; j < 4; ++j)
                acc[i][j] = __builtin_amdgcn_mfma_f32_16x16x32_bf16(af[i], bfr[j], acc[i][j], 0, 0, 0);
    }
    const int col = lane & 15;
    const int rb = (lane >> 4) * 4;
#pragma unroll
    for (int i = 0; i < 4; ++i)
#pragma unroll
        for (int j = 0; j < 4; ++j) {
            int cc = n0 + j * 16 + col;
            float bias = bdt[cc];
#pragma unroll
            for (int r = 0; r < 4; ++r) {
                float v = acc[i][j][r] + bias;
                float sp = (v > 20.f) ? v : log1pf(__expf(v));
                dt[(size_t)(m0 + i * 16 + rb + r) * 4096 + cc] = (__bf16)sp;
            }
        }
}

// ---------------------------------------------------------------------------
// Chunked scan, 16 chunks x 128 steps. Block = 64 d x 128 t (4 waves; each
// wave: 16 d x 4 n-groups, 4 states/thread). Grid = 2b x 16c x 32 = 1024.
// ---------------------------------------------------------------------------
__global__ __launch_bounds__(256) void scan_p1(const __bf16* __restrict__ xz,
                                               const __bf16* __restrict__ xq,
                                               const __bf16* __restrict__ xp,
                                               const float* __restrict__ A_log,
                                               float* __restrict__ h_end,
                                               float* __restrict__ dtsum) {
    __shared__ uint32_t s_dtx[128][64];   // (x<<16)|dt
    __shared__ __bf16 s_B[128][16];
    const int tid = threadIdx.x;
    const int bi = blockIdx.x;
    const int b = bi >> 9, c = (bi >> 5) & 15, d0 = (bi & 31) * 64;
    const int row0 = b * 2048 + c * 128;

#pragma unroll
    for (int i = 0; i < 8; ++i) {
        int w = i * 256 + tid;
        int t = w >> 4, g = (w & 15) * 4;
        bf16x4 dt4 = *(const bf16x4*)(xz + (size_t)(row0 + t) * 4096 + d0 + g);
        bf16x4 x4  = *(const bf16x4*)(xq + (size_t)(row0 + t) * 2048 + d0 + g);
        u32x4 o;
#pragma unroll
        for (int k = 0; k < 4; ++k) o[k] = packbf(dt4[k], x4[k]);
        *(u32x4*)&s_dtx[t][g] = o;
    }
#pragma unroll
    for (int i = 0; i < 2; ++i) {
        int w = i * 256 + tid;
        int t = w >> 2, g = (w & 3) * 4;
        *(bf16x4*)&s_B[t][g] = *(const bf16x4*)(xp + (size_t)(row0 + t) * 96 + 64 + g);
    }
    const int lane = tid & 63, wave = tid >> 6;
    const int dcol = wave * 16 + (lane >> 2);
    const int d = d0 + dcol;
    const int ng = lane & 3;
    f32x4 Al = *(const f32x4*)(A_log + (size_t)d * 16 + ng * 4);
    float Adn[4];
#pragma unroll
    for (int j = 0; j < 4; ++j) Adn[j] = -__expf(Al[j]);
    __syncthreads();

    float h[4] = {0.f, 0.f, 0.f, 0.f};
    float ds = 0.f;
#pragma unroll 8
    for (int t = 0; t < 128; ++t) {
        uint32_t u = s_dtx[t][dcol];
        float dt = lo2f(u), x = hi2f(u);
        bf16x4 B4 = *(const bf16x4*)&s_B[t][ng * 4];
        float p = dt * x;
#pragma unroll
        for (int j = 0; j < 4; ++j) {
            float dA = __expf(dt * Adn[j]);
            h[j] = fmaf(dA, h[j], p * (float)B4[j]);
        }
        ds += dt;
    }
    size_t base = (size_t)(b * 16 + c) * 2048 + d;
    f32x4 hv = {h[0], h[1], h[2], h[3]};
    *(f32x4*)(h_end + base * 16 + ng * 4) = hv;
    if (ng == 0) dtsum[base] = ds;
}

// Phase 2: prefix over 16 chunks per (b,d,n). 65536 threads.
__global__ __launch_bounds__(256) void scan_p2(const float* __restrict__ A_log,
                                               const float* __restrict__ dtsum,
                                               const float* __restrict__ h_end,
                                               float* __restrict__ h_in) {
    int idx = blockIdx.x * 256 + threadIdx.x;
    int b = idx >> 15, rem = idx & 32767;
    int d = rem >> 4;
    float Adn = -__expf(A_log[rem]);
    float h = 0.f;
#pragma unroll
    for (int c = 0; c < 16; ++c) {
        size_t base = ((size_t)(b * 16 + c) << 15) + rem;
        h_in[base] = h;
        float P = __expf(Adn * dtsum[((size_t)(b * 16 + c) << 11) + d]);
        h = fmaf(P, h, h_end[base]);
    }
}

// Phase 3: rerun from h_in, y = (C.h + D*x)*silu(z) -> xq in-place.
__global__ __launch_bounds__(256) void scan_p3(const __bf16* __restrict__ xz,
                                               __bf16* __restrict__ xq,
                                               const __bf16* __restrict__ xp,
                                               const float* __restrict__ A_log,
                                               const float* __restrict__ Dp,
                                               const float* __restrict__ h_in) {
    __shared__ uint32_t s_dtx[128][64];   // (x<<16)|dt
    __shared__ uint32_t s_BC[128][16];    // (C<<16)|B
    __shared__ __bf16 s_zy[128][64];      // z, overwritten by y
    const int tid = threadIdx.x;
    const int bi = blockIdx.x;
    const int b = bi >> 9, c = (bi >> 5) & 15, d0 = (bi & 31) * 64;
    const int row0 = b * 2048 + c * 128;

#pragma unroll
    for (int i = 0; i < 8; ++i) {
        int w = i * 256 + tid;
        int t = w >> 4, g = (w & 15) * 4;
        bf16x4 dt4 = *(const bf16x4*)(xz + (size_t)(row0 + t) * 4096 + d0 + g);
        bf16x4 x4  = *(const bf16x4*)(xq + (size_t)(row0 + t) * 2048 + d0 + g);
        u32x4 o;
#pragma unroll
        for (int k = 0; k < 4; ++k) o[k] = packbf(dt4[k], x4[k]);
        *(u32x4*)&s_dtx[t][g] = o;
    }
#pragma unroll
    for (int i = 0; i < 2; ++i) {
        int w = i * 256 + tid;
        int t = w >> 2, g = (w & 3) * 4;
        bf16x4 B4 = *(const bf16x4*)(xp + (size_t)(row0 + t) * 96 + 64 + g);
        bf16x4 C4 = *(const bf16x4*)(xp + (size_t)(row0 + t) * 96 + 80 + g);
        u32x4 o;
#pragma unroll
        for (int k = 0; k < 4; ++k) o[k] = packbf(B4[k], C4[k]);
        *(u32x4*)&s_BC[t][g] = o;
    }
#pragma unroll
    for (int i = 0; i < 4; ++i) {
        int w = i * 256 + tid;
        int t = w >> 3, g = (w & 7) * 8;
        *(bf16x8*)&s_zy[t][g] =
            *(const bf16x8*)(xz + (size_t)(row0 + t) * 4096 + 2048 + d0 + g);
    }
    const int lane = tid & 63, wave = tid >> 6;
    const int dcol = wave * 16 + (lane >> 2);
    const int d = d0 + dcol;
    const int ng = lane & 3;
    f32x4 Al = *(const f32x4*)(A_log + (size_t)d * 16 + ng * 4);
    float Adn[4];
#pragma unroll
    for (int j = 0; j < 4; ++j) Adn[j] = -__expf(Al[j]);
    const float Dd = Dp[d];
    f32x4 h = *(const f32x4*)(h_in + ((size_t)(b * 16 + c) * 2048 + d) * 16 + ng * 4);
    __syncthreads();

#pragma unroll 8
    for (int t = 0; t < 128; ++t) {
        uint32_t u = s_dtx[t][dcol];
        float dt = lo2f(u), x = hi2f(u);
        u32x4 bc = *(const u32x4*)&s_BC[t][ng * 4];
        float p = dt * x;
        float cs;
#pragma unroll
        for (int j = 0; j < 4; ++j) {
            float Bv = lo2f(bc[j]), Cv = hi2f(bc[j]);
            float dA = __expf(dt * Adn[j]);
            h[j] = fmaf(dA, h[j], p * Bv);
            cs = (j == 0) ? h[0] * Cv : fmaf(h[j], Cv, cs);
        }
        cs = qp_add<0xB1>(cs);   // xor1
        cs = qp_add<0x4E>(cs);   // xor2 -> all 4 lanes have sum over 16 n
        if (ng == 0) {
            float zv = (float)s_zy[t][dcol];
            float yv = (cs + Dd * x) * (zv / (1.f + __expf(-zv)));
            s_zy[t][dcol] = (__bf16)yv;
        }
    }
    __syncthreads();
#pragma unroll
    for (int i = 0; i < 4; ++i) {
        int w = i * 256 + tid;
        int t = w >> 3, g = (w & 7) * 8;
        *(bf16x8*)(xq + (size_t)(row0 + t) * 2048 + d0 + g) = *(bf16x8*)&s_zy[t][g];
    }
}

// ---------------------------------------------------------------------------
extern "C" void kernel_launch(void* const* d_in, const int* in_sizes, int n_in,
                              void* d_out, int out_size, void* d_ws, size_t ws_size,
                              hipStream_t stream) {
    const float* u      = (const float*)d_in[0];
    const float* W_in   = (const float*)d_in[1];
    const float* W_out  = (const float*)d_in[2];
    const float* conv_w = (const float*)d_in[3];
    const float* conv_b = (const float*)d_in[4];
    const float* W_x    = (const float*)d_in[5];
    const float* W_dt   = (const float*)d_in[6];
    const float* b_dt   = (const float*)d_in[7];
    const float* A_log  = (const float*)d_in[8];
    const float* D_p    = (const float*)d_in[9];
    float* out = (float*)d_out;

    // ws (bf16), ~64.4 MB:
    __bf16* xz   = (__bf16*)d_ws;                   // [4096][4096]: x_in->dt | z
    __bf16* xq   = xz  + (size_t)4096 * 4096;       // [4096][2048]: x -> y
    __bf16* xp   = xq  + (size_t)4096 * 2048;       // [4096][96]
    __bf16* Wib  = xp  + (size_t)4096 * 96;         // W_in  bf16 [4096][1024]
    __bf16* Wob  = Wib + (size_t)4096 * 1024;       // W_out bf16 [1024][2048]
    __bf16* Wxb  = Wob + (size_t)1024 * 2048;       // W_x   bf16 [96][2048]
    __bf16* Wdtb = Wxb + (size_t)96 * 2048;         // W_dt  bf16 [2048][64]

    // d_out doubles as scratch:
    __bf16* ub    = (__bf16*)d_out;                 // u bf16 (dead after gemm1)
    float* xpart  = (float*)d_out;                  // [8][4096][96] partials (12.6MB)
    float* dtsum  = (float*)d_out;                  // 256 KB (after xpart dead)
    float* h_end  = (float*)d_out + 2097152;        // 4 MB @ 8MB
    float* h_in   = (float*)d_out + 3145728;        // 4 MB @ 12MB

    cvt_kernel<<<2048, 256, 0, stream>>>(u, ub, 524288);
    cvt_kernel<<<2048, 256, 0, stream>>>(W_in, Wib, 524288);
    cvt_kernel<<<1024, 256, 0, stream>>>(W_out, Wob, 262144);
    cvt_kernel<<<96, 256, 0, stream>>>(W_x, Wxb, 24576);
    cvt_kernel<<<64, 256, 0, stream>>>(W_dt, Wdtb, 16384);

    // 1. xz = ub @ Wib^T  (M=4096,N=4096,K=1024)
    gemm_async_bf<<<dim3(32, 32), 256, 0, stream>>>(ub, Wib, xz, 1024, 4096);
    // 2. x = silu(conv(x_in))
    conv_silu_kernel<<<4096, 256, 0, stream>>>(xz, conv_w, conv_b, xq);
    // 3. x_p split-K (overwrites ub scratch) + reduce
    gemm_xp_split<<<dim3(64, 8), 256, 0, stream>>>(xq, Wxb, xpart);
    xp_reduce<<<4096, 128, 0, stream>>>(xpart, xp);
    // 4. dt -> xz[:, :2048]
    gemm_dt<<<dim3(32, 16), 256, 0, stream>>>(xp, Wdtb, b_dt, xz);
    // 5. chunked scan
    scan_p1<<<1024, 256, 0, stream>>>(xz, xq, xp, A_log, h_end, dtsum);
    scan_p2<<<256, 256, 0, stream>>>(A_log, dtsum, h_end, h_in);
    scan_p3<<<1024, 256, 0, stream>>>(xz, xq, xp, A_log, D_p, h_in);
    // 6. out = y @ Wob^T  (M=4096,N=1024,K=2048)
    gemm_async_f32<<<dim3(32, 8), 256, 0, stream>>>(xq, Wob, out, 2048, 1024);
}